// Round 6
// baseline (428.775 us; speedup 1.0000x reference)
//
#include <hip/hip_runtime.h>
#include <hip/hip_bf16.h>
#include <cstdint>
#include <cstddef>

#define HDIM 4096
#define MROWS 8192
#define LN_EPS 1e-5f

typedef __bf16 bf16_t;
typedef __bf16 bf16x4_t __attribute__((ext_vector_type(4)));
typedef __bf16 bf16x8_t __attribute__((ext_vector_type(8)));
typedef float f32x4_t __attribute__((ext_vector_type(4)));

typedef const __attribute__((address_space(1))) void gvoid_t;
typedef __attribute__((address_space(3))) void lvoid_t;

__device__ __forceinline__ float softplus_f(float x) {
    return fmaxf(x, 0.f) + log1pf(expf(-fabsf(x)));
}

// ---- W = mu + softplus(rho)*eps  -> bf16 ----
__global__ __launch_bounds__(256) void wgen_kernel(
    const float* __restrict__ mu, const float* __restrict__ rho,
    const float* __restrict__ eps, bf16_t* __restrict__ W)
{
    int i = (blockIdx.x * 256 + threadIdx.x) * 4;
    float4 m = *(const float4*)(mu + i);
    float4 r = *(const float4*)(rho + i);
    float4 e = *(const float4*)(eps + i);
    bf16x4_t o;
    o[0] = (bf16_t)(m.x + softplus_f(r.x) * e.x);
    o[1] = (bf16_t)(m.y + softplus_f(r.y) * e.y);
    o[2] = (bf16_t)(m.z + softplus_f(r.z) * e.z);
    o[3] = (bf16_t)(m.w + softplus_f(r.w) * e.w);
    *(bf16x4_t*)(W + i) = o;
}

// ---- bias = b_mu + softplus(b_rho)*eps_b  (fp32) ----
__global__ __launch_bounds__(256) void biasgen_kernel(
    const float* __restrict__ mu, const float* __restrict__ rho,
    const float* __restrict__ eps, float* __restrict__ b)
{
    int i = blockIdx.x * 256 + threadIdx.x;
    b[i] = mu[i] + softplus_f(rho[i]) * eps[i];
}

// ---- LayerNorm per row of 4096, fp32 in -> bf16 out ----
__global__ __launch_bounds__(256) void ln_kernel(
    const float* __restrict__ x, const float* __restrict__ gamma,
    const float* __restrict__ beta, bf16_t* __restrict__ h)
{
    int row = blockIdx.x;
    const float* xr = x + (size_t)row * HDIM;
    int t = threadIdx.x;
    float4 v[4];
    float s = 0.f, s2 = 0.f;
#pragma unroll
    for (int j = 0; j < 4; ++j) {
        v[j] = *(const float4*)(xr + j * 1024 + t * 4);
        s  += v[j].x + v[j].y + v[j].z + v[j].w;
        s2 += v[j].x * v[j].x + v[j].y * v[j].y + v[j].z * v[j].z + v[j].w * v[j].w;
    }
#pragma unroll
    for (int off = 32; off > 0; off >>= 1) {
        s  += __shfl_down(s, off);
        s2 += __shfl_down(s2, off);
    }
    __shared__ float ps[4], ps2[4];
    if ((t & 63) == 0) { ps[t >> 6] = s; ps2[t >> 6] = s2; }
    __syncthreads();
    float tot  = ps[0] + ps[1] + ps[2] + ps[3];
    float tot2 = ps2[0] + ps2[1] + ps2[2] + ps2[3];
    float mean = tot * (1.f / HDIM);
    float var  = tot2 * (1.f / HDIM) - mean * mean;
    float rstd = rsqrtf(var + LN_EPS);
    bf16_t* hr = h + (size_t)row * HDIM;
#pragma unroll
    for (int j = 0; j < 4; ++j) {
        int c = j * 1024 + t * 4;
        float4 g  = *(const float4*)(gamma + c);
        float4 bb = *(const float4*)(beta + c);
        bf16x4_t o;
        o[0] = (bf16_t)((v[j].x - mean) * rstd * g.x + bb.x);
        o[1] = (bf16_t)((v[j].y - mean) * rstd * g.y + bb.y);
        o[2] = (bf16_t)((v[j].z - mean) * rstd * g.z + bb.z);
        o[3] = (bf16_t)((v[j].w - mean) * rstd * g.w + bb.w);
        *(bf16x4_t*)(hr + c) = o;
    }
}

__device__ __forceinline__ void gload_lds16(const bf16_t* g, const char* l) {
    __builtin_amdgcn_global_load_lds((gvoid_t*)g, (lvoid_t*)l, 16, 0, 0);
}

// Inline-asm LDS read: compiler cannot attach conservative vmcnt/lgkm waits
// to it (it can't see the dependency on global_load_lds writes). Ordering is
// enforced by surrounding sched_barrier(0) + hand-placed s_waitcnt.
__device__ __forceinline__ bf16x8_t ds_read_b128_raw(const char* p) {
    f32x4_t r;
    asm volatile("ds_read_b128 %0, %1" : "=v"(r) : "v"((lvoid_t*)p));
    return __builtin_bit_cast(bf16x8_t, r);
}

// st-style LDS swizzle: flip byte bits 4,5 with bits 7,8. Involution,
// confined to 512B blocks.
__device__ __forceinline__ int swz(int x) { return x ^ ((x >> 3) & 0x30); }

// ---- GEMM: out[m][o] = x[m][o] + gelu( sum_k h[m][k]*W[o][k] + bias[o] ) ----
// 256x256 tile, BK=32, 8 waves (2Mx4N), 4-deep LDS ring (4 x 32KB).
// Template-style phases with HAND-CONTROLLED waits (no compiler waits on LDS
// reads — they are inline asm): per phase {asm ds_reads; stage half-tile;
// lgkmcnt(0); sched_barrier; 16 MFMA; barrier}; vmcnt(8) once per K-tile.
//
// Hazard ledger:
//  WAR(stage): X(t)/Y(t) stage into buf[(t-1)&3]; all reads of that buffer
//    (iter t-1) were drained by lgkmcnt(0) before B1(t-1)/B2(t-1); stages
//    issue after crossing B2(t-1) -> no wave can see its reads clobbered.
//  RAW(tile ready): vmcnt(8) before B2(t) leaves exactly A,B of tiles
//    t+2,t+3 (8 loads) in flight => tile t+1 fully landed; X(t+1) reads it
//    only after crossing B2(t).
__global__ __launch_bounds__(512, 2) void gemm_kernel(
    const bf16_t* __restrict__ A,   // [8192][4096] h (bf16)
    const bf16_t* __restrict__ B,   // [4096][4096] W (bf16, row=o col=k)
    const float* __restrict__ bias, // [4096]
    const float* __restrict__ xres, // [8192][4096] residual fp32
    float* __restrict__ out)        // [8192][4096]
{
    __shared__ char lds[131072];    // ring: buf b at b*32768; A at +0, B at +16KB

    const int tid  = threadIdx.x;
    const int lane = tid & 63, w = tid >> 6;
    const int g = lane >> 4, fr = lane & 15;
    const int wm = w >> 2, wn = w & 3;   // wave grid 2(M) x 4(N)

    // T1: bijective XCD swizzle (512 blocks, 512%8==0)
    int bid = blockIdx.x;
    int wg  = (bid & 7) * 64 + (bid >> 3);
    const int tileN = (wg & 15) * 256;
    const int tileM = (wg >> 4) * 256;

    // staging: linear LDS dest D = r*8192 + w*1024 + lane*16 per region;
    // LDS[D] holds linear-image value at S = swz(D).
    const bf16_t* srcA[2];
    const bf16_t* srcB[2];
    int ldstA[2], ldstB[2];
#pragma unroll
    for (int r = 0; r < 2; ++r) {
        int D = r * 8192 + w * 1024 + lane * 16;
        int S = swz(D);
        int row = S >> 6, colel = (S & 63) >> 1;
        srcA[r] = A + (size_t)(tileM + row) * HDIM + colel;
        srcB[r] = B + (size_t)(tileN + row) * HDIM + colel;
        ldstA[r] = r * 8192 + w * 1024;
        ldstB[r] = 16384 + r * 8192 + w * 1024;
    }

    // fragment ds_read offsets (swizzled, relative to buffer base)
    int aoff[8], boff[4];
#pragma unroll
    for (int m = 0; m < 8; ++m)
        aoff[m] = swz(wm * 8192 + m * 1024 + fr * 64 + g * 16);
#pragma unroll
    for (int n = 0; n < 4; ++n)
        boff[n] = 16384 + swz(wn * 4096 + n * 1024 + fr * 64 + g * 16);

    f32x4_t acc[8][4] = {};
    const int NT = HDIM / 32;  // 128 K-tiles

    bf16x8_t af0, af1, af2, af3, af4, af5, af6, af7;
    bf16x8_t bv0, bv1, bv2, bv3;

#define STAGE_A(bb, kofs)                                        \
    do {                                                         \
        gload_lds16(srcA[0] + (kofs), &lds[(bb) + ldstA[0]]);    \
        gload_lds16(srcA[1] + (kofs), &lds[(bb) + ldstA[1]]);    \
    } while (0)
#define STAGE_B(bb, kofs)                                        \
    do {                                                         \
        gload_lds16(srcB[0] + (kofs), &lds[(bb) + ldstB[0]]);    \
        gload_lds16(srcB[1] + (kofs), &lds[(bb) + ldstB[1]]);    \
    } while (0)
#define CL(AF, R)                                                               \
    acc[R][0] = __builtin_amdgcn_mfma_f32_16x16x32_bf16(AF, bv0, acc[R][0], 0, 0, 0); \
    acc[R][1] = __builtin_amdgcn_mfma_f32_16x16x32_bf16(AF, bv1, acc[R][1], 0, 0, 0); \
    acc[R][2] = __builtin_amdgcn_mfma_f32_16x16x32_bf16(AF, bv2, acc[R][2], 0, 0, 0); \
    acc[R][3] = __builtin_amdgcn_mfma_f32_16x16x32_bf16(AF, bv3, acc[R][3], 0, 0, 0);
#define SCHEDB __builtin_amdgcn_sched_barrier(0)
#define BARRIER do { __builtin_amdgcn_s_barrier(); SCHEDB; } while (0)
#define LGKM0 do { asm volatile("s_waitcnt lgkmcnt(0)" ::: "memory"); SCHEDB; } while (0)
#define VMCNT8 do { asm volatile("s_waitcnt vmcnt(8)" ::: "memory"); SCHEDB; } while (0)

    // prologue: stage tiles 0,1,2; drain tile 0 (keep A1,B1,A2,B2 = 8)
    STAGE_A(0, 0);      STAGE_B(0, 0);
    STAGE_A(32768, 32); STAGE_B(32768, 32);
    STAGE_A(65536, 64); STAGE_B(65536, 64);
    asm volatile("s_waitcnt vmcnt(8)" ::: "memory");
    BARRIER;

#pragma unroll 1
    for (int t = 0; t < NT; ++t) {
        const char* buf = &lds[(t & 3) * 32768];
        const int sb = ((t + 3) & 3) * 32768;     // stage dest: buf[(t-1)&3]
        const int sk = ((t + 3) & (NT - 1)) * 32; // tail wrap: staged, never read

        // ---- phase X: reads af0-3 + bv (tile t), stage A(t+3), 16 MFMA ----
        af0 = ds_read_b128_raw(buf + aoff[0]);
        af1 = ds_read_b128_raw(buf + aoff[1]);
        af2 = ds_read_b128_raw(buf + aoff[2]);
        af3 = ds_read_b128_raw(buf + aoff[3]);
        bv0 = ds_read_b128_raw(buf + boff[0]);
        bv1 = ds_read_b128_raw(buf + boff[1]);
        bv2 = ds_read_b128_raw(buf + boff[2]);
        bv3 = ds_read_b128_raw(buf + boff[3]);
        STAGE_A(sb, sk);
        SCHEDB;
        LGKM0;
        __builtin_amdgcn_s_setprio(1);
        CL(af0, 0) CL(af1, 1) CL(af2, 2) CL(af3, 3)
        __builtin_amdgcn_s_setprio(0);
        SCHEDB;
        BARRIER;   // B1(t)

        // ---- phase Y: reads af4-7 (tile t), stage B(t+3), 16 MFMA ----
        af4 = ds_read_b128_raw(buf + aoff[4]);
        af5 = ds_read_b128_raw(buf + aoff[5]);
        af6 = ds_read_b128_raw(buf + aoff[6]);
        af7 = ds_read_b128_raw(buf + aoff[7]);
        STAGE_B(sb, sk);
        SCHEDB;
        LGKM0;
        __builtin_amdgcn_s_setprio(1);
        CL(af4, 4) CL(af5, 5) CL(af6, 6) CL(af7, 7)
        __builtin_amdgcn_s_setprio(0);
        SCHEDB;
        VMCNT8;    // drain tile t+1's stages; keep t+2,t+3 (8) in flight
        BARRIER;   // B2(t)
    }
#undef STAGE_A
#undef STAGE_B

    // epilogue: bias + exact GELU + residual, fp32 out
    // C/D layout: col = lane&15, row = (lane>>4)*4 + j
    const int col0 = tileN + wn * 64 + fr;
    const int row0 = tileM + wm * 128 + g * 4;
#pragma unroll
    for (int n = 0; n < 4; ++n) {
        float bvv = bias[col0 + n * 16];
#pragma unroll
        for (int m = 0; m < 8; ++m) {
#pragma unroll
            for (int j = 0; j < 4; ++j) {
                size_t idx = (size_t)(row0 + m * 16 + j) * HDIM + (col0 + n * 16);
                float v = acc[m][n][j] + bvv;
                float ge = 0.5f * v * (1.0f + erff(v * 0.70710678118654752f));
                out[idx] = xres[idx] + ge;
            }
        }
    }
}

extern "C" void kernel_launch(void* const* d_in, const int* in_sizes, int n_in,
                              void* d_out, int out_size, void* d_ws, size_t ws_size,
                              hipStream_t stream) {
    const float* x        = (const float*)d_in[0];
    const float* ln_gamma = (const float*)d_in[1];
    const float* ln_beta  = (const float*)d_in[2];
    const float* w_mu     = (const float*)d_in[3];
    const float* w_rho    = (const float*)d_in[4];
    const float* b_mu     = (const float*)d_in[5];
    const float* b_rho    = (const float*)d_in[6];
    const float* eps_w    = (const float*)d_in[7];
    const float* eps_b    = (const float*)d_in[8];
    float* out = (float*)d_out;

    char* ws = (char*)d_ws;
    bf16_t* h_bf16 = (bf16_t*)ws;                              // 64 MiB
    bf16_t* W_bf16 = (bf16_t*)(ws + 67108864);                 // 32 MiB
    float*  bias   = (float*)(ws + 67108864 + 33554432);       // 16 KiB

    wgen_kernel<<<16384, 256, 0, stream>>>(w_mu, w_rho, eps_w, W_bf16);
    biasgen_kernel<<<16, 256, 0, stream>>>(b_mu, b_rho, eps_b, bias);
    ln_kernel<<<MROWS, 256, 0, stream>>>(x, ln_gamma, ln_beta, h_bf16);
    gemm_kernel<<<512, 512, 0, stream>>>(h_bf16, W_bf16, bias, x, out);
}

// Round 7
// 416.773 us; speedup vs baseline: 1.0288x; 1.0288x over previous
//
#include <hip/hip_runtime.h>
#include <hip/hip_bf16.h>
#include <cstdint>
#include <cstddef>

#define HDIM 4096
#define MROWS 8192
#define LN_EPS 1e-5f

typedef __bf16 bf16_t;
typedef __bf16 bf16x4_t __attribute__((ext_vector_type(4)));
typedef __bf16 bf16x8_t __attribute__((ext_vector_type(8)));
typedef float f32x4_t __attribute__((ext_vector_type(4)));

typedef const __attribute__((address_space(1))) void gvoid_t;
typedef __attribute__((address_space(3))) void lvoid_t;

__device__ __forceinline__ float softplus_f(float x) {
    return fmaxf(x, 0.f) + log1pf(expf(-fabsf(x)));
}

// ---- W = mu + softplus(rho)*eps  -> bf16 ----
__global__ __launch_bounds__(256) void wgen_kernel(
    const float* __restrict__ mu, const float* __restrict__ rho,
    const float* __restrict__ eps, bf16_t* __restrict__ W)
{
    int i = (blockIdx.x * 256 + threadIdx.x) * 4;
    float4 m = *(const float4*)(mu + i);
    float4 r = *(const float4*)(rho + i);
    float4 e = *(const float4*)(eps + i);
    bf16x4_t o;
    o[0] = (bf16_t)(m.x + softplus_f(r.x) * e.x);
    o[1] = (bf16_t)(m.y + softplus_f(r.y) * e.y);
    o[2] = (bf16_t)(m.z + softplus_f(r.z) * e.z);
    o[3] = (bf16_t)(m.w + softplus_f(r.w) * e.w);
    *(bf16x4_t*)(W + i) = o;
}

// ---- bias = b_mu + softplus(b_rho)*eps_b  (fp32) ----
__global__ __launch_bounds__(256) void biasgen_kernel(
    const float* __restrict__ mu, const float* __restrict__ rho,
    const float* __restrict__ eps, float* __restrict__ b)
{
    int i = blockIdx.x * 256 + threadIdx.x;
    b[i] = mu[i] + softplus_f(rho[i]) * eps[i];
}

// ---- LayerNorm per row of 4096, fp32 in -> bf16 out ----
__global__ __launch_bounds__(256) void ln_kernel(
    const float* __restrict__ x, const float* __restrict__ gamma,
    const float* __restrict__ beta, bf16_t* __restrict__ h)
{
    int row = blockIdx.x;
    const float* xr = x + (size_t)row * HDIM;
    int t = threadIdx.x;
    float4 v[4];
    float s = 0.f, s2 = 0.f;
#pragma unroll
    for (int j = 0; j < 4; ++j) {
        v[j] = *(const float4*)(xr + j * 1024 + t * 4);
        s  += v[j].x + v[j].y + v[j].z + v[j].w;
        s2 += v[j].x * v[j].x + v[j].y * v[j].y + v[j].z * v[j].z + v[j].w * v[j].w;
    }
#pragma unroll
    for (int off = 32; off > 0; off >>= 1) {
        s  += __shfl_down(s, off);
        s2 += __shfl_down(s2, off);
    }
    __shared__ float ps[4], ps2[4];
    if ((t & 63) == 0) { ps[t >> 6] = s; ps2[t >> 6] = s2; }
    __syncthreads();
    float tot  = ps[0] + ps[1] + ps[2] + ps[3];
    float tot2 = ps2[0] + ps2[1] + ps2[2] + ps2[3];
    float mean = tot * (1.f / HDIM);
    float var  = tot2 * (1.f / HDIM) - mean * mean;
    float rstd = rsqrtf(var + LN_EPS);
    bf16_t* hr = h + (size_t)row * HDIM;
#pragma unroll
    for (int j = 0; j < 4; ++j) {
        int c = j * 1024 + t * 4;
        float4 g  = *(const float4*)(gamma + c);
        float4 bb = *(const float4*)(beta + c);
        bf16x4_t o;
        o[0] = (bf16_t)((v[j].x - mean) * rstd * g.x + bb.x);
        o[1] = (bf16_t)((v[j].y - mean) * rstd * g.y + bb.y);
        o[2] = (bf16_t)((v[j].z - mean) * rstd * g.z + bb.z);
        o[3] = (bf16_t)((v[j].w - mean) * rstd * g.w + bb.w);
        *(bf16x4_t*)(hr + c) = o;
    }
}

__device__ __forceinline__ void gload_lds16(const bf16_t* g, const char* l) {
    __builtin_amdgcn_global_load_lds((gvoid_t*)g, (lvoid_t*)l, 16, 0, 0);
}

// Inline-asm LDS read: keeps wait insertion in OUR hands (counted lgkm).
__device__ __forceinline__ bf16x8_t ds_read_b128_raw(const char* p) {
    f32x4_t r;
    asm volatile("ds_read_b128 %0, %1" : "=v"(r) : "v"((lvoid_t*)p));
    return __builtin_bit_cast(bf16x8_t, r);
}

// st-style LDS swizzle: flip byte bits 4,5 with bits 7,8. Involution,
// confined to 512B blocks.
__device__ __forceinline__ int swz(int x) { return x ^ ((x >> 3) & 0x30); }

// ---- GEMM: out[m][o] = x[m][o] + gelu( sum_k h[m][k]*W[o][k] + bias[o] ) ----
// 256x256 tile, BK=32, 8 waves (2Mx4N), 4-deep LDS ring (4 x 32KB).
// COUNTED-lgkm one-phase-lookahead schedule (T4 proper): each phase issues
// the NEXT cluster's ds_reads, waits only for the PREVIOUS issue group
// (lgkmcnt(4)/(8), never 0), so MFMA overlaps LDS reads within each wave.
// One barrier + one vmcnt(4) per K-tile.
//
// Counter ledger (per wave; ds and vm counters are independent):
//  at X(t) entry: 8 ds outstanding (P/R-set from Y(t-1)). issue 4 -> 12;
//    lgkmcnt(4) drains the 8 -> MFMA(af0-3) runs with 4 in flight.
//  at Y(t): 4 outstanding; issue 8 (tile t+1) -> 12; lgkmcnt(8) drains 4
//    -> MFMA(af4-7) runs with 8 in flight.
//  vmcnt(4) end-Y(t): stages: iter t-1 kept 4 (tile t+2), iter t adds 4
//    (tile t+3) -> 8; drain to 4 => tile t+2 landed, read in Y(t+1) after
//    the barrier. Tile t+1 (read in Y(t)) was drained at end-Y(t-1).
//  WAR: stages at iter t hit buf[(t-1)&3]; last reads of it (X(t-1) qa)
//    drained by Y(t-1) lgkmcnt(8) before that wave's end-Y(t-1) barrier.
__global__ __launch_bounds__(512, 2) void gemm_kernel(
    const bf16_t* __restrict__ A,   // [8192][4096] h (bf16)
    const bf16_t* __restrict__ B,   // [4096][4096] W (bf16, row=o col=k)
    const float* __restrict__ bias, // [4096]
    const float* __restrict__ xres, // [8192][4096] residual fp32
    float* __restrict__ out)        // [8192][4096]
{
    __shared__ char lds[131072];    // ring: buf b at b*32768; A at +0, B at +16KB

    const int tid  = threadIdx.x;
    const int lane = tid & 63, w = tid >> 6;
    const int g = lane >> 4, fr = lane & 15;
    const int wm = w >> 2, wn = w & 3;   // wave grid 2(M) x 4(N)

    // T1: bijective XCD swizzle (512 blocks, 512%8==0)
    int bid = blockIdx.x;
    int wg  = (bid & 7) * 64 + (bid >> 3);
    const int tileN = (wg & 15) * 256;
    const int tileM = (wg >> 4) * 256;

    // staging: linear LDS dest D = r*8192 + w*1024 + lane*16 per region;
    // LDS[D] holds linear-image value at S = swz(D).
    const bf16_t* srcA[2];
    const bf16_t* srcB[2];
    int ldstA[2], ldstB[2];
#pragma unroll
    for (int r = 0; r < 2; ++r) {
        int D = r * 8192 + w * 1024 + lane * 16;
        int S = swz(D);
        int row = S >> 6, colel = (S & 63) >> 1;
        srcA[r] = A + (size_t)(tileM + row) * HDIM + colel;
        srcB[r] = B + (size_t)(tileN + row) * HDIM + colel;
        ldstA[r] = r * 8192 + w * 1024;
        ldstB[r] = 16384 + r * 8192 + w * 1024;
    }

    // fragment ds_read offsets (swizzled, relative to buffer base)
    int aoff[8], boff[4];
#pragma unroll
    for (int m = 0; m < 8; ++m)
        aoff[m] = swz(wm * 8192 + m * 1024 + fr * 64 + g * 16);
#pragma unroll
    for (int n = 0; n < 4; ++n)
        boff[n] = 16384 + swz(wn * 4096 + n * 1024 + fr * 64 + g * 16);

    f32x4_t acc[8][4] = {};
    const int NT = HDIM / 32;  // 128 K-tiles

    // register sets: P = cur low-A + B; Q = cur high-A; R = next low-A + B
    bf16x8_t pa0, pa1, pa2, pa3, pv0, pv1, pv2, pv3;
    bf16x8_t qa0, qa1, qa2, qa3;
    bf16x8_t ra0, ra1, ra2, ra3, rv0, rv1, rv2, rv3;

#define STAGE_A(bb, kofs)                                        \
    do {                                                         \
        gload_lds16(srcA[0] + (kofs), &lds[(bb) + ldstA[0]]);    \
        gload_lds16(srcA[1] + (kofs), &lds[(bb) + ldstA[1]]);    \
    } while (0)
#define STAGE_B(bb, kofs)                                        \
    do {                                                         \
        gload_lds16(srcB[0] + (kofs), &lds[(bb) + ldstB[0]]);    \
        gload_lds16(srcB[1] + (kofs), &lds[(bb) + ldstB[1]]);    \
    } while (0)
#define CL(AF, V, R)                                                            \
    acc[R][0] = __builtin_amdgcn_mfma_f32_16x16x32_bf16(AF, V##0, acc[R][0], 0, 0, 0); \
    acc[R][1] = __builtin_amdgcn_mfma_f32_16x16x32_bf16(AF, V##1, acc[R][1], 0, 0, 0); \
    acc[R][2] = __builtin_amdgcn_mfma_f32_16x16x32_bf16(AF, V##2, acc[R][2], 0, 0, 0); \
    acc[R][3] = __builtin_amdgcn_mfma_f32_16x16x32_bf16(AF, V##3, acc[R][3], 0, 0, 0);
#define SCHEDB __builtin_amdgcn_sched_barrier(0)
#define LGKM(n) do { asm volatile("s_waitcnt lgkmcnt(" #n ")" ::: "memory"); SCHEDB; } while (0)

    // RDQ: 4 high-A reads of tile tc. RDPR: 8 low-A+B reads of tile tc.
#define RDQ(tc)                                                       \
    do { const char* bp_ = &lds[((tc) & 3) * 32768];                  \
        qa0 = ds_read_b128_raw(bp_ + aoff[4]);                        \
        qa1 = ds_read_b128_raw(bp_ + aoff[5]);                        \
        qa2 = ds_read_b128_raw(bp_ + aoff[6]);                        \
        qa3 = ds_read_b128_raw(bp_ + aoff[7]); } while (0)
#define RDN(tc, SA, SV)                                               \
    do { const char* bp_ = &lds[((tc) & 3) * 32768];                  \
        SA##0 = ds_read_b128_raw(bp_ + aoff[0]);                      \
        SA##1 = ds_read_b128_raw(bp_ + aoff[1]);                      \
        SA##2 = ds_read_b128_raw(bp_ + aoff[2]);                      \
        SA##3 = ds_read_b128_raw(bp_ + aoff[3]);                      \
        SV##0 = ds_read_b128_raw(bp_ + boff[0]);                      \
        SV##1 = ds_read_b128_raw(bp_ + boff[1]);                      \
        SV##2 = ds_read_b128_raw(bp_ + boff[2]);                      \
        SV##3 = ds_read_b128_raw(bp_ + boff[3]); } while (0)

    // One K-tile with current set (CA=low-A prefix, CV=B prefix) reading the
    // NEXT tile's low-A+B into (NA, NV).
#define KTILE(tc, CA, CV, NA, NV)                                     \
    do {                                                              \
        const int sb_ = (((tc) + 3) & 3) * 32768;                     \
        const int sk_ = (((tc) + 3) & (NT - 1)) * 32;                 \
        /* phase X */                                                 \
        RDQ(tc);                                                      \
        STAGE_A(sb_, sk_);                                            \
        SCHEDB;                                                       \
        LGKM(4);                                                      \
        __builtin_amdgcn_s_setprio(1);                                \
        CL(CA##0, CV, 0) CL(CA##1, CV, 1) CL(CA##2, CV, 2) CL(CA##3, CV, 3) \
        __builtin_amdgcn_s_setprio(0);                                \
        SCHEDB;                                                       \
        /* phase Y */                                                 \
        RDN((tc) + 1, NA, NV);                                        \
        STAGE_B(sb_, sk_);                                            \
        SCHEDB;                                                       \
        LGKM(8);                                                      \
        __builtin_amdgcn_s_setprio(1);                                \
        CL(qa0, CV, 4) CL(qa1, CV, 5) CL(qa2, CV, 6) CL(qa3, CV, 7)   \
        __builtin_amdgcn_s_setprio(0);                                \
        SCHEDB;                                                       \
        asm volatile("s_waitcnt vmcnt(4)" ::: "memory");              \
        __builtin_amdgcn_s_barrier();                                 \
        SCHEDB;                                                       \
    } while (0)

    // prologue: stage tiles 0,1,2; drain tiles 0,1 (keep A2,B2 = 4)
    STAGE_A(0, 0);      STAGE_B(0, 0);
    STAGE_A(32768, 32); STAGE_B(32768, 32);
    STAGE_A(65536, 64); STAGE_B(65536, 64);
    asm volatile("s_waitcnt vmcnt(4)" ::: "memory");
    __builtin_amdgcn_s_barrier();
    SCHEDB;
    RDN(0, pa, pv);   // 8 ds outstanding: steady-state X-entry invariant
    SCHEDB;

#pragma unroll 1
    for (int t = 0; t < NT; t += 2) {
        KTILE(t,     pa, pv, ra, rv);   // even: cur=P, next=R
        KTILE(t + 1, ra, rv, pa, pv);   // odd:  cur=R, next=P
    }
#undef KTILE
#undef RDQ
#undef RDN
#undef STAGE_A
#undef STAGE_B

    // epilogue: bias + exact GELU + residual, fp32 out
    // C/D layout: col = lane&15, row = (lane>>4)*4 + j
    const int col0 = tileN + wn * 64 + fr;
    const int row0 = tileM + wm * 128 + g * 4;
#pragma unroll
    for (int n = 0; n < 4; ++n) {
        float bvv = bias[col0 + n * 16];
#pragma unroll
        for (int m = 0; m < 8; ++m) {
#pragma unroll
            for (int j = 0; j < 4; ++j) {
                size_t idx = (size_t)(row0 + m * 16 + j) * HDIM + (col0 + n * 16);
                float v = acc[m][n][j] + bvv;
                float ge = 0.5f * v * (1.0f + erff(v * 0.70710678118654752f));
                out[idx] = xres[idx] + ge;
            }
        }
    }
}

extern "C" void kernel_launch(void* const* d_in, const int* in_sizes, int n_in,
                              void* d_out, int out_size, void* d_ws, size_t ws_size,
                              hipStream_t stream) {
    const float* x        = (const float*)d_in[0];
    const float* ln_gamma = (const float*)d_in[1];
    const float* ln_beta  = (const float*)d_in[2];
    const float* w_mu     = (const float*)d_in[3];
    const float* w_rho    = (const float*)d_in[4];
    const float* b_mu     = (const float*)d_in[5];
    const float* b_rho    = (const float*)d_in[6];
    const float* eps_w    = (const float*)d_in[7];
    const float* eps_b    = (const float*)d_in[8];
    float* out = (float*)d_out;

    char* ws = (char*)d_ws;
    bf16_t* h_bf16 = (bf16_t*)ws;                              // 64 MiB
    bf16_t* W_bf16 = (bf16_t*)(ws + 67108864);                 // 32 MiB
    float*  bias   = (float*)(ws + 67108864 + 33554432);       // 16 KiB

    wgen_kernel<<<16384, 256, 0, stream>>>(w_mu, w_rho, eps_w, W_bf16);
    biasgen_kernel<<<16, 256, 0, stream>>>(b_mu, b_rho, eps_b, bias);
    ln_kernel<<<MROWS, 256, 0, stream>>>(x, ln_gamma, ln_beta, h_bf16);
    gemm_kernel<<<512, 512, 0, stream>>>(h_bf16, W_bf16, bias, x, out);
}